// Round 15
// baseline (80.242 us; speedup 1.0000x reference)
//
#include <hip/hip_runtime.h>
#include <hip/hip_bf16.h>
#include <stdint.h>

#define B_ 4
#define T_ 2048
#define F_ 512
#define H_ 8
#define DK_ 64
#define BT_ (B_*T_)   // 8192

typedef short bf16x8 __attribute__((ext_vector_type(8)));
typedef short s16x4 __attribute__((ext_vector_type(4)));
typedef float f32x4 __attribute__((ext_vector_type(4)));
typedef float f32x16 __attribute__((ext_vector_type(16)));

__device__ __forceinline__ unsigned short f2bf(float f) {
  union { float f; unsigned u; } v; v.f = f;
  return (unsigned short)((v.u + 0x7fffu + ((v.u >> 16) & 1u)) >> 16);
}

__device__ __forceinline__ unsigned cvtpk(float lo, float hi) {
  unsigned w;
  asm("v_cvt_pk_bf16_f32 %0, %1, %2" : "=v"(w) : "v"(lo), "v"(hi));
  return w;
}

__device__ __forceinline__ void gload_lds16(const void* g, void* l) {
  __builtin_amdgcn_global_load_lds((const __attribute__((address_space(1))) void*)g,
                                   (__attribute__((address_space(3))) void*)l, 16, 0, 0);
}

// ---------------- fused: weight fp32->bf16 conversion + mask scan ----------------
__global__ void convert_scan(const float* __restrict__ wq, const float* __restrict__ wk,
                             const float* __restrict__ wv, const float* __restrict__ wo,
                             const int* __restrict__ mask,
                             unsigned short* __restrict__ dst, int* __restrict__ invidx,
                             int* __restrict__ nbuf) {
  const int seg = blockIdx.y;
  const int tid = threadIdx.x;
  if (seg == 4) {
    if (blockIdx.x >= 4) return;
    const int b = blockIdx.x;
    __shared__ int cnt[256];
    const int base = b * T_ + tid * 8;
    int4 a = *(const int4*)(mask + base);
    int4 d = *(const int4*)(mask + base + 4);
    int m[8] = {a.x, a.y, a.z, a.w, d.x, d.y, d.z, d.w};
    int c = 0;
#pragma unroll
    for (int i = 0; i < 8; ++i) c += (m[i] != 0);
    cnt[tid] = c;
    __syncthreads();
    for (int off = 1; off < 256; off <<= 1) {
      int v = (tid >= off) ? cnt[tid - off] : 0;
      __syncthreads();
      cnt[tid] += v;
      __syncthreads();
    }
    int excl = cnt[tid] - c;
#pragma unroll
    for (int i = 0; i < 8; ++i)
      if (m[i]) { invidx[b * T_ + excl] = tid * 8 + i; ++excl; }
    if (tid == 255) nbuf[b] = cnt[255];
    return;
  }
  const float* src = seg == 0 ? wq : (seg == 1 ? wk : (seg == 2 ? wv : wo));
  unsigned short* out = dst + (size_t)seg * F_ * F_;
  const int idx = (blockIdx.x * 256 + tid) * 8;
  float4 a = *(const float4*)(src + idx);
  float4 b = *(const float4*)(src + idx + 4);
  union { unsigned w[4]; bf16x8 v; } t;
  t.w[0] = cvtpk(a.x, a.y); t.w[1] = cvtpk(a.z, a.w);
  t.w[2] = cvtpk(b.x, b.y); t.w[3] = cvtpk(b.z, b.w);
  *(bf16x8*)(out + idx) = t.v;
}

// ---------------- fused QKV projection GEMM ----------------
__global__ __launch_bounds__(256, 3) void gemm_qkv(
    const float* __restrict__ qin, const float* __restrict__ kin, const float* __restrict__ vin,
    const unsigned short* __restrict__ Wbase,
    const float* __restrict__ bq, const float* __restrict__ bk, const float* __restrict__ bv,
    const int* __restrict__ invidx, const int* __restrict__ nbuf,
    unsigned short* __restrict__ projq, unsigned short* __restrict__ kc,
    unsigned short* __restrict__ vt, float qscale) {
  const int id0 = blockIdx.x;
  const int id = (id0 & 7) * 96 + (id0 >> 3);   // bijective: 768 = 8*96
  const int p = id >> 8, l = id & 255;
  const int tid = threadIdx.x;
  const int wid = tid >> 6, lane = tid & 63;
  const int lr = lane & 15, lg = lane >> 4;
  const int wr = wid >> 1, wc = wid & 1;
  const int n0 = (l & 3) * 128;

  const float* Af;
  const float* bias;
  float sc = 1.0f;
  int obase, j0 = 0, b = 0, nb = T_;
  if (p == 0) {
    obase = (l >> 2) * 128;
    Af = qin; bias = bq; sc = qscale;
  } else {
    b = l >> 6;
    j0 = ((l >> 2) & 15) * 128;
    nb = nbuf[b];
    if (j0 >= ((nb + 63) & ~63)) return;   // tile entirely beyond compacted range
    obase = b * T_ + j0;
    Af = (p == 1) ? kin : vin;
    bias = (p == 1) ? bk : bv;
  }
  const unsigned short* W = Wbase + (size_t)p * F_ * F_;

  __shared__ __align__(16) unsigned short As[128 * 64];
  __shared__ __align__(16) unsigned short Bs[128 * 64];

  int srcrow[4];
#pragma unroll
  for (int i = 0; i < 4; ++i) {
    const int r = (i * 256 + tid) >> 3;
    if (p == 0) srcrow[i] = obase + r;
    else {
      int j = j0 + r;
      if (j >= nb) j = nb - 1;               // clamp: duplicate a real row (masked later)
      srcrow[i] = b * T_ + invidx[b * T_ + j];
    }
  }

  float4 aR[4][2];
  auto loadA = [&](int k0) {
#pragma unroll
    for (int i = 0; i < 4; ++i) {
      const int s = (i * 256 + tid) & 7;
      const float* sp = Af + (size_t)srcrow[i] * F_ + k0 + s * 8;
      aR[i][0] = *(const float4*)sp;
      aR[i][1] = *(const float4*)(sp + 4);
    }
  };
  auto writeA = [&]() {
#pragma unroll
    for (int i = 0; i < 4; ++i) {
      const int ch = i * 256 + tid;
      const int r = ch >> 3, s = ch & 7;
      union { unsigned w[4]; bf16x8 v; } t;
      t.w[0] = cvtpk(aR[i][0].x, aR[i][0].y); t.w[1] = cvtpk(aR[i][0].z, aR[i][0].w);
      t.w[2] = cvtpk(aR[i][1].x, aR[i][1].y); t.w[3] = cvtpk(aR[i][1].z, aR[i][1].w);
      *(bf16x8*)&As[r * 64 + ((s ^ (r & 7)) * 8)] = t.v;
    }
  };
  auto stageB = [&](int k0) {
#pragma unroll
    for (int i = 0; i < 4; ++i) {
      const int ch = i * 256 + tid;
      const int r = ch >> 3, s = ch & 7;
      gload_lds16(W + (size_t)(n0 + r) * F_ + k0 + ((s ^ (r & 7)) * 8),
                  &Bs[(i * 256 + wid * 64) * 8]);
    }
  };

  f32x4 acc[4][4] = {};
  loadA(0);
  for (int k0 = 0; k0 < F_; k0 += 64) {
    stageB(k0);
    writeA();
    __syncthreads();
    if (k0 + 64 < F_) loadA(k0 + 64);

#pragma unroll
    for (int kk = 0; kk < 2; ++kk) {
      bf16x8 af[4], bf[4];
      const int slotA = (kk * 4 + lg) ^ (lr & 7);
#pragma unroll
      for (int m = 0; m < 4; ++m)
        af[m] = *(const bf16x8*)&As[(wr * 64 + m * 16 + lr) * 64 + slotA * 8];
#pragma unroll
      for (int n = 0; n < 4; ++n)
        bf[n] = *(const bf16x8*)&Bs[(wc * 64 + n * 16 + lr) * 64 + slotA * 8];
#pragma unroll
      for (int m = 0; m < 4; ++m)
#pragma unroll
        for (int n = 0; n < 4; ++n)
          acc[m][n] = __builtin_amdgcn_mfma_f32_16x16x32_bf16(af[m], bf[n], acc[m][n], 0, 0, 0);
    }
    __syncthreads();
  }

  if (p == 2) {
    // transposed write: Vt[((b*8 + h)*64 + d)*T + kv],  h = col>>6, d = col&63
#pragma unroll
    for (int n = 0; n < 4; ++n) {
      const int col = n0 + wc * 64 + n * 16 + lr;
      const float bvv = bias[col];
      unsigned short* vrow = vt + ((size_t)(b * 8 + (col >> 6)) * 64 + (col & 63)) * T_;
#pragma unroll
      for (int m = 0; m < 4; ++m) {
        const int kv = j0 + wr * 64 + m * 16 + lg * 4;
        union { unsigned short u[4]; s16x4 v; } ov;
#pragma unroll
        for (int j = 0; j < 4; ++j) ov.u[j] = f2bf(acc[m][n][j] + bvv);
        *(s16x4*)(vrow + kv) = ov.v;
      }
    }
  } else {
    unsigned short* outp = (p == 0) ? projq : kc;
#pragma unroll
    for (int n = 0; n < 4; ++n) {
      const int col = n0 + wc * 64 + n * 16 + lr;
      const float bvv = bias[col];
#pragma unroll
      for (int m = 0; m < 4; ++m) {
        const int rbase = obase + wr * 64 + m * 16 + lg * 4;
#pragma unroll
        for (int j = 0; j < 4; ++j)
          outp[(size_t)(rbase + j) * F_ + col] = f2bf((acc[m][n][j] + bvv) * sc);
      }
    }
  }
}

// ---------------- output projection GEMM (bf16 A, fp32 out), 64x128 tile, 2 blocks/CU ----------------
__global__ __launch_bounds__(256, 3) void gemm_out(
    const unsigned short* __restrict__ Abf, const unsigned short* __restrict__ W,
    const float* __restrict__ bias, float* __restrict__ outf) {
  const int id0 = blockIdx.x;
  const int l = (id0 & 7) * 64 + (id0 >> 3);   // bijective: 512 = 8*64
  const int m0 = (l >> 2) * 64, n0 = (l & 3) * 128;
  const int tid = threadIdx.x;
  const int wid = tid >> 6, lane = tid & 63;
  const int lr = lane & 15, lg = lane >> 4;
  const int wr = wid >> 1, wc = wid & 1;

  __shared__ __align__(16) unsigned short As[64 * 64];
  __shared__ __align__(16) unsigned short Bs[128 * 64];

  auto stage = [&](int k0) {
#pragma unroll
    for (int i = 0; i < 2; ++i) {
      const int ch = i * 256 + tid;
      const int r = ch >> 3, s = ch & 7;
      gload_lds16(Abf + (size_t)(m0 + r) * F_ + k0 + ((s ^ (r & 7)) * 8),
                  &As[(i * 256 + wid * 64) * 8]);
    }
#pragma unroll
    for (int i = 0; i < 4; ++i) {
      const int ch = i * 256 + tid;
      const int r = ch >> 3, s = ch & 7;
      gload_lds16(W + (size_t)(n0 + r) * F_ + k0 + ((s ^ (r & 7)) * 8),
                  &Bs[(i * 256 + wid * 64) * 8]);
    }
  };

  f32x4 acc[2][4] = {};
  for (int k0 = 0; k0 < F_; k0 += 64) {
    stage(k0);
    __syncthreads();
#pragma unroll
    for (int kk = 0; kk < 2; ++kk) {
      bf16x8 af[2], bf[4];
      const int slotA = (kk * 4 + lg) ^ (lr & 7);
#pragma unroll
      for (int m = 0; m < 2; ++m)
        af[m] = *(const bf16x8*)&As[(wr * 32 + m * 16 + lr) * 64 + slotA * 8];
#pragma unroll
      for (int n = 0; n < 4; ++n)
        bf[n] = *(const bf16x8*)&Bs[(wc * 64 + n * 16 + lr) * 64 + slotA * 8];
#pragma unroll
      for (int m = 0; m < 2; ++m)
#pragma unroll
        for (int n = 0; n < 4; ++n)
          acc[m][n] = __builtin_amdgcn_mfma_f32_16x16x32_bf16(af[m], bf[n], acc[m][n], 0, 0, 0);
    }
    __syncthreads();
  }

#pragma unroll
  for (int n = 0; n < 4; ++n) {
    const int col = n0 + wc * 64 + n * 16 + lr;
    const float bvv = bias[col];
#pragma unroll
    for (int m = 0; m < 2; ++m) {
      const int rbase = m0 + wr * 32 + m * 16 + lg * 4;
#pragma unroll
      for (int j = 0; j < 4; ++j)
        outf[(size_t)(rbase + j) * F_ + col] = acc[m][n][j] + bvv;
    }
  }
}

// ---------------- flash attention: 4 waves x 64 q-rows, LDS-BW-halved ----------------
// attn is LDS-read-BW-bound: K/V tiles are SHARED across q-rows, so every wave re-reads
// the full 32 KB tile (512 KB/tile/CU at 8 waves). Fix: 64 q-rows per wave (two 32-col
// MFMA groups) — kf/vfr fragments are read ONCE and feed BOTH q-groups, halving per-CU
// LDS reads. 4 waves x 64 q = 256 q/block, grid 256 = 1 block/CU, 1 wave/SIMD (~350 VGPR,
// under the 512 no-spill line). 3-deep buffer ring + counted vmcnt(8); fixed-shift
// softmax; ones-MFMA denominator.
__global__ __launch_bounds__(256, 1) void attn_kernel(
    const unsigned short* __restrict__ Qp,
    const unsigned short* __restrict__ Kp,
    const unsigned short* __restrict__ Vt,
    const int* __restrict__ nbuf,
    unsigned short* __restrict__ X) {
  const int tid = threadIdx.x, wid = tid >> 6, lane = tid & 63;
  const int la = lane & 31, hi = lane >> 5;
  const int id = blockIdx.x;                  // 0..255, XCD-aware bijective swizzle
  const int swz = (id & 7) * 32 + (id >> 3);
  const int bh = swz >> 3, qb = swz & 7;
  const int b = bh >> 3, h = bh & 7;
  const int qbase = qb * 256 + wid * 64;
  const int nb = nbuf[b];
  const int nt = (nb + 127) >> 7;             // compacted 128-tile count

  __shared__ __align__(16) unsigned short Ks[3][128 * 64];  // [kv][dk], 8-slot XOR swizzle
  __shared__ __align__(16) unsigned short Vs[3][64 * 128];  // [d][kv], 16-slot XOR swizzle

  bf16x8 qf[2][4];
#pragma unroll
  for (int gq = 0; gq < 2; ++gq)
#pragma unroll
    for (int kk = 0; kk < 4; ++kk)
      qf[gq][kk] = *(const bf16x8*)(Qp + (size_t)(b * T_ + qbase + gq * 32 + la) * F_ +
                                    h * DK_ + kk * 16 + hi * 8);

  union { unsigned short u[8]; bf16x8 v; } ones;
#pragma unroll
  for (int j = 0; j < 8; ++j) ones.u[j] = 0x3F80;   // bf16 1.0

  f32x16 oacc[2][2] = {};
  f32x16 dacc[2] = {};

  auto stage = [&](int buf, int kv0) {
#pragma unroll
    for (int i = 0; i < 4; ++i) {              // K: 1024 chunks of 16B over 256 threads
      const int ch = i * 256 + tid;
      const int r = ch >> 3, s = ch & 7;
      gload_lds16(Kp + (size_t)(b * T_ + kv0 + r) * F_ + h * DK_ + ((s ^ (r & 7)) * 8),
                  &Ks[buf][(i * 256 + wid * 64) * 8]);
    }
#pragma unroll
    for (int i = 0; i < 4; ++i) {              // V: 1024 chunks of 16B
      const int ch = i * 256 + tid;
      const int d = ch >> 4, s2 = ch & 15;
      gload_lds16(Vt + ((size_t)bh * DK_ + d) * T_ + kv0 + ((s2 ^ (d & 15)) * 8),
                  &Vs[buf][(i * 256 + wid * 64) * 8]);
    }
  };

  if (nt > 0) {
    stage(0, 0);                                // 8 loads/thread
    if (nt > 1) stage(1, 128);

    int cur = 0;
    for (int t = 0; t < nt; ++t) {
      // own stage(t) landed; stage(t+1)'s 8 loads may stay in flight (T4 counted vmcnt)
      if (t + 1 < nt) asm volatile("s_waitcnt vmcnt(8)" ::: "memory");
      else            asm volatile("s_waitcnt vmcnt(0)" ::: "memory");
      __builtin_amdgcn_s_barrier();
      __builtin_amdgcn_sched_barrier(0);
      if (t + 2 < nt) {
        int nxt = cur + 2; if (nxt >= 3) nxt -= 3;
        stage(nxt, (t + 2) * 128);
      }
      const int kv0 = t * 128;

      // K fragments once (64 VGPR), reused by both q-groups
      bf16x8 kf[4][4];
#pragma unroll
      for (int n = 0; n < 4; ++n)
#pragma unroll
        for (int kk = 0; kk < 4; ++kk)
          kf[n][kk] = *(const bf16x8*)&Ks[cur][(n * 32 + la) * 64 + ((((kk << 1) | hi) ^ (la & 7)) * 8)];

      // S^T = K · Q^T for both q-groups
      f32x16 sb[2][4];
      __builtin_amdgcn_s_setprio(1);
#pragma unroll
      for (int gq = 0; gq < 2; ++gq)
#pragma unroll
        for (int n = 0; n < 4; ++n) {
          f32x16 s = {};
#pragma unroll
          for (int kk = 0; kk < 4; ++kk)
            s = __builtin_amdgcn_mfma_f32_32x32x16_bf16(kf[n][kk], qf[gq][kk], s, 0, 0, 0);
          sb[gq][n] = s;
        }
      __builtin_amdgcn_s_setprio(0);

      // P = exp2(S), tail-masked to 0 via index compare
      if (kv0 + 128 > nb) {
        const int kvb = kv0 + 4 * hi;
#pragma unroll
        for (int gq = 0; gq < 2; ++gq)
#pragma unroll
          for (int n = 0; n < 4; ++n)
#pragma unroll
            for (int r = 0; r < 16; ++r) {
              const int kv = kvb + n * 32 + (r & 3) + 8 * (r >> 2);
              if (kv >= nb) sb[gq][n][r] = -__builtin_inff();
            }
      }
#pragma unroll
      for (int gq = 0; gq < 2; ++gq)
#pragma unroll
        for (int n = 0; n < 4; ++n)
#pragma unroll
          for (int r = 0; r < 16; ++r)
            sb[gq][n][r] = __builtin_amdgcn_exp2f(sb[gq][n][r]);

      // pack P pairs to bf16 words; exchange halves via permlane32_swap
      unsigned lowr[2][4][2][2], uppr[2][4][2][2];
#pragma unroll
      for (int gq = 0; gq < 2; ++gq)
#pragma unroll
        for (int n = 0; n < 4; ++n)
#pragma unroll
          for (int gg = 0; gg < 2; ++gg)
#pragma unroll
            for (int hh = 0; hh < 2; ++hh) {
              unsigned xE = cvtpk(sb[gq][n][4 * (2 * gg) + 2 * hh], sb[gq][n][4 * (2 * gg) + 2 * hh + 1]);
              unsigned xO = cvtpk(sb[gq][n][4 * (2 * gg + 1) + 2 * hh], sb[gq][n][4 * (2 * gg + 1) + 2 * hh + 1]);
              asm("v_permlane32_swap_b32 %0, %1" : "+v"(xE), "+v"(xO));
              lowr[gq][n][gg][hh] = xE;
              uppr[gq][n][gg][hh] = xO;
            }

      // O^T += V^T · P^T; V fragment read ONCE per (kt,m), feeds both q-groups.
#pragma unroll
      for (int kt = 0; kt < 8; ++kt) {
        const int n = kt >> 1, gg = kt & 1;
        union { unsigned w[4]; bf16x8 v; } pf0, pf1;
        pf0.w[0] = lowr[0][n][gg][0]; pf0.w[1] = lowr[0][n][gg][1];
        pf0.w[2] = uppr[0][n][gg][0]; pf0.w[3] = uppr[0][n][gg][1];
        pf1.w[0] = lowr[1][n][gg][0]; pf1.w[1] = lowr[1][n][gg][1];
        pf1.w[2] = uppr[1][n][gg][0]; pf1.w[3] = uppr[1][n][gg][1];
        __builtin_amdgcn_s_setprio(1);
        dacc[0] = __builtin_amdgcn_mfma_f32_32x32x16_bf16(ones.v, pf0.v, dacc[0], 0, 0, 0);
        dacc[1] = __builtin_amdgcn_mfma_f32_32x32x16_bf16(ones.v, pf1.v, dacc[1], 0, 0, 0);
#pragma unroll
        for (int m = 0; m < 2; ++m) {
          const int d = m * 32 + la;
          bf16x8 vfr = *(const bf16x8*)&Vs[cur][d * 128 + ((((kt << 1) | hi) ^ (d & 15)) * 8)];
          oacc[0][m] = __builtin_amdgcn_mfma_f32_32x32x16_bf16(vfr, pf0.v, oacc[0][m], 0, 0, 0);
          oacc[1][m] = __builtin_amdgcn_mfma_f32_32x32x16_bf16(vfr, pf1.v, oacc[1][m], 0, 0, 0);
        }
        __builtin_amdgcn_s_setprio(0);
      }

      cur = (cur + 1 < 3) ? cur + 1 : 0;
    }
  }

#pragma unroll
  for (int gq = 0; gq < 2; ++gq) {
    const float inv = 1.0f / fmaxf(dacc[gq][0], 1e-37f);
#pragma unroll
    for (int m = 0; m < 2; ++m)
#pragma unroll
      for (int g = 0; g < 4; ++g) {
        union { unsigned short u[4]; s16x4 v; } ov;
#pragma unroll
        for (int j = 0; j < 4; ++j) ov.u[j] = f2bf(oacc[gq][m][4 * g + j] * inv);
        *(s16x4*)(X + (size_t)(b * T_ + qbase + gq * 32 + la) * F_ + h * DK_ +
                  m * 32 + 8 * g + 4 * hi) = ov.v;
      }
  }
}

// ---------------- launcher ----------------
extern "C" void kernel_launch(void* const* d_in, const int* in_sizes, int n_in,
                              void* d_out, int out_size, void* d_ws, size_t ws_size,
                              hipStream_t stream) {
  const float* q  = (const float*)d_in[0];
  const float* k  = (const float*)d_in[1];
  const float* v  = (const float*)d_in[2];
  const int* mask = (const int*)d_in[3];
  const float* Wq = (const float*)d_in[4];
  const float* bq = (const float*)d_in[5];
  const float* Wk = (const float*)d_in[6];
  const float* bk = (const float*)d_in[7];
  const float* Wv = (const float*)d_in[8];
  const float* bv = (const float*)d_in[9];
  const float* Wo = (const float*)d_in[10];
  const float* bo = (const float*)d_in[11];
  float* out = (float*)d_out;

  unsigned short* ws = (unsigned short*)d_ws;
  unsigned short* wts   = ws;                               // 4*F*F = 1,048,576 us
  unsigned short* projq = wts + (size_t)4 * F_ * F_;        // BT*F (Q)
  unsigned short* kc    = projq + (size_t)BT_ * F_;         // BT*F (compacted K)
  unsigned short* vt    = kc + (size_t)BT_ * F_;            // BT*F (compacted V^T per head)
  unsigned short* xbuf  = vt + (size_t)BT_ * F_;            // BT*F (attn output)
  int* invidx  = (int*)(xbuf + (size_t)BT_ * F_);           // B*T int
  int* nbuf    = invidx + BT_;                              // B int

  const float kQScale = 0.18033688011112042f;  // (1/sqrt(64)) * log2(e)

  convert_scan<<<dim3(128, 5, 1), 256, 0, stream>>>(
      Wq, Wk, Wv, Wo, mask, wts, invidx, nbuf);
  gemm_qkv<<<dim3(768, 1, 1), 256, 0, stream>>>(
      q, k, v, wts, bq, bk, bv, invidx, nbuf, projq, kc, vt, kQScale);
  attn_kernel<<<dim3(256, 1, 1), 256, 0, stream>>>(
      projq, kc, vt, nbuf, xbuf);
  gemm_out<<<dim3(512, 1, 1), 256, 0, stream>>>(
      xbuf, wts + (size_t)3 * F_ * F_, bo, out);
}

// Round 16
// 72.053 us; speedup vs baseline: 1.1137x; 1.1137x over previous
//
#include <hip/hip_runtime.h>
#include <hip/hip_bf16.h>
#include <stdint.h>

#define B_ 4
#define T_ 2048
#define F_ 512
#define H_ 8
#define DK_ 64
#define BT_ (B_*T_)   // 8192

typedef short bf16x8 __attribute__((ext_vector_type(8)));
typedef short s16x4 __attribute__((ext_vector_type(4)));
typedef float f32x4 __attribute__((ext_vector_type(4)));
typedef float f32x16 __attribute__((ext_vector_type(16)));

__device__ __forceinline__ unsigned short f2bf(float f) {
  union { float f; unsigned u; } v; v.f = f;
  return (unsigned short)((v.u + 0x7fffu + ((v.u >> 16) & 1u)) >> 16);
}

__device__ __forceinline__ unsigned cvtpk(float lo, float hi) {
  unsigned w;
  asm("v_cvt_pk_bf16_f32 %0, %1, %2" : "=v"(w) : "v"(lo), "v"(hi));
  return w;
}

__device__ __forceinline__ void gload_lds16(const void* g, void* l) {
  __builtin_amdgcn_global_load_lds((const __attribute__((address_space(1))) void*)g,
                                   (__attribute__((address_space(3))) void*)l, 16, 0, 0);
}

// ---------------- fused: weight fp32->bf16 conversion + mask scan ----------------
__global__ void convert_scan(const float* __restrict__ wq, const float* __restrict__ wk,
                             const float* __restrict__ wv, const float* __restrict__ wo,
                             const int* __restrict__ mask,
                             unsigned short* __restrict__ dst, int* __restrict__ invidx,
                             int* __restrict__ nbuf) {
  const int seg = blockIdx.y;
  const int tid = threadIdx.x;
  if (seg == 4) {
    if (blockIdx.x >= 4) return;
    const int b = blockIdx.x;
    __shared__ int cnt[256];
    const int base = b * T_ + tid * 8;
    int4 a = *(const int4*)(mask + base);
    int4 d = *(const int4*)(mask + base + 4);
    int m[8] = {a.x, a.y, a.z, a.w, d.x, d.y, d.z, d.w};
    int c = 0;
#pragma unroll
    for (int i = 0; i < 8; ++i) c += (m[i] != 0);
    cnt[tid] = c;
    __syncthreads();
    for (int off = 1; off < 256; off <<= 1) {
      int v = (tid >= off) ? cnt[tid - off] : 0;
      __syncthreads();
      cnt[tid] += v;
      __syncthreads();
    }
    int excl = cnt[tid] - c;
#pragma unroll
    for (int i = 0; i < 8; ++i)
      if (m[i]) { invidx[b * T_ + excl] = tid * 8 + i; ++excl; }
    if (tid == 255) nbuf[b] = cnt[255];
    return;
  }
  const float* src = seg == 0 ? wq : (seg == 1 ? wk : (seg == 2 ? wv : wo));
  unsigned short* out = dst + (size_t)seg * F_ * F_;
  const int idx = (blockIdx.x * 256 + tid) * 8;
  float4 a = *(const float4*)(src + idx);
  float4 b = *(const float4*)(src + idx + 4);
  union { unsigned w[4]; bf16x8 v; } t;
  t.w[0] = cvtpk(a.x, a.y); t.w[1] = cvtpk(a.z, a.w);
  t.w[2] = cvtpk(b.x, b.y); t.w[3] = cvtpk(b.z, b.w);
  *(bf16x8*)(out + idx) = t.v;
}

// ---------------- fused QKV projection GEMM ----------------
// XCD-locality swizzle; p=0: Q (pre-scaled); p=1: K gathered -> kc; p=2: V gathered -> Vt
// transposed. K/V tiles written through ceil256(nb) (clamped dup rows) so attn's 256-wide
// staging never reads non-finite memory.
__global__ __launch_bounds__(256, 3) void gemm_qkv(
    const float* __restrict__ qin, const float* __restrict__ kin, const float* __restrict__ vin,
    const unsigned short* __restrict__ Wbase,
    const float* __restrict__ bq, const float* __restrict__ bk, const float* __restrict__ bv,
    const int* __restrict__ invidx, const int* __restrict__ nbuf,
    unsigned short* __restrict__ projq, unsigned short* __restrict__ kc,
    unsigned short* __restrict__ vt, float qscale) {
  const int id0 = blockIdx.x;
  const int id = (id0 & 7) * 96 + (id0 >> 3);   // bijective: 768 = 8*96
  const int p = id >> 8, l = id & 255;
  const int tid = threadIdx.x;
  const int wid = tid >> 6, lane = tid & 63;
  const int lr = lane & 15, lg = lane >> 4;
  const int wr = wid >> 1, wc = wid & 1;
  const int n0 = (l & 3) * 128;

  const float* Af;
  const float* bias;
  float sc = 1.0f;
  int obase, j0 = 0, b = 0, nb = T_;
  if (p == 0) {
    obase = (l >> 2) * 128;
    Af = qin; bias = bq; sc = qscale;
  } else {
    b = l >> 6;
    j0 = ((l >> 2) & 15) * 128;
    nb = nbuf[b];
    if (j0 >= ((nb + 255) & ~255)) return;   // cover through ceil256(nb) for attn staging
    obase = b * T_ + j0;
    Af = (p == 1) ? kin : vin;
    bias = (p == 1) ? bk : bv;
  }
  const unsigned short* W = Wbase + (size_t)p * F_ * F_;

  __shared__ __align__(16) unsigned short As[128 * 64];
  __shared__ __align__(16) unsigned short Bs[128 * 64];

  int srcrow[4];
#pragma unroll
  for (int i = 0; i < 4; ++i) {
    const int r = (i * 256 + tid) >> 3;
    if (p == 0) srcrow[i] = obase + r;
    else {
      int j = j0 + r;
      if (j >= nb) j = nb - 1;               // clamp: duplicate a real row (masked later)
      srcrow[i] = b * T_ + invidx[b * T_ + j];
    }
  }

  float4 aR[4][2];
  auto loadA = [&](int k0) {
#pragma unroll
    for (int i = 0; i < 4; ++i) {
      const int s = (i * 256 + tid) & 7;
      const float* sp = Af + (size_t)srcrow[i] * F_ + k0 + s * 8;
      aR[i][0] = *(const float4*)sp;
      aR[i][1] = *(const float4*)(sp + 4);
    }
  };
  auto writeA = [&]() {
#pragma unroll
    for (int i = 0; i < 4; ++i) {
      const int ch = i * 256 + tid;
      const int r = ch >> 3, s = ch & 7;
      union { unsigned w[4]; bf16x8 v; } t;
      t.w[0] = cvtpk(aR[i][0].x, aR[i][0].y); t.w[1] = cvtpk(aR[i][0].z, aR[i][0].w);
      t.w[2] = cvtpk(aR[i][1].x, aR[i][1].y); t.w[3] = cvtpk(aR[i][1].z, aR[i][1].w);
      *(bf16x8*)&As[r * 64 + ((s ^ (r & 7)) * 8)] = t.v;
    }
  };
  auto stageB = [&](int k0) {
#pragma unroll
    for (int i = 0; i < 4; ++i) {
      const int ch = i * 256 + tid;
      const int r = ch >> 3, s = ch & 7;
      gload_lds16(W + (size_t)(n0 + r) * F_ + k0 + ((s ^ (r & 7)) * 8),
                  &Bs[(i * 256 + wid * 64) * 8]);
    }
  };

  f32x4 acc[4][4] = {};
  loadA(0);
  for (int k0 = 0; k0 < F_; k0 += 64) {
    stageB(k0);
    writeA();
    __syncthreads();
    if (k0 + 64 < F_) loadA(k0 + 64);

#pragma unroll
    for (int kk = 0; kk < 2; ++kk) {
      bf16x8 af[4], bf[4];
      const int slotA = (kk * 4 + lg) ^ (lr & 7);
#pragma unroll
      for (int m = 0; m < 4; ++m)
        af[m] = *(const bf16x8*)&As[(wr * 64 + m * 16 + lr) * 64 + slotA * 8];
#pragma unroll
      for (int n = 0; n < 4; ++n)
        bf[n] = *(const bf16x8*)&Bs[(wc * 64 + n * 16 + lr) * 64 + slotA * 8];
#pragma unroll
      for (int m = 0; m < 4; ++m)
#pragma unroll
        for (int n = 0; n < 4; ++n)
          acc[m][n] = __builtin_amdgcn_mfma_f32_16x16x32_bf16(af[m], bf[n], acc[m][n], 0, 0, 0);
    }
    __syncthreads();
  }

  if (p == 2) {
    // transposed write: Vt[((b*8 + h)*64 + d)*T + kv],  h = col>>6, d = col&63
#pragma unroll
    for (int n = 0; n < 4; ++n) {
      const int col = n0 + wc * 64 + n * 16 + lr;
      const float bvv = bias[col];
      unsigned short* vrow = vt + ((size_t)(b * 8 + (col >> 6)) * 64 + (col & 63)) * T_;
#pragma unroll
      for (int m = 0; m < 4; ++m) {
        const int kv = j0 + wr * 64 + m * 16 + lg * 4;
        union { unsigned short u[4]; s16x4 v; } ov;
#pragma unroll
        for (int j = 0; j < 4; ++j) ov.u[j] = f2bf(acc[m][n][j] + bvv);
        *(s16x4*)(vrow + kv) = ov.v;
      }
    }
  } else {
    unsigned short* outp = (p == 0) ? projq : kc;
#pragma unroll
    for (int n = 0; n < 4; ++n) {
      const int col = n0 + wc * 64 + n * 16 + lr;
      const float bvv = bias[col];
#pragma unroll
      for (int m = 0; m < 4; ++m) {
        const int rbase = obase + wr * 64 + m * 16 + lg * 4;
#pragma unroll
        for (int j = 0; j < 4; ++j)
          outp[(size_t)(rbase + j) * F_ + col] = f2bf((acc[m][n][j] + bvv) * sc);
      }
    }
  }
}

// ---------------- output projection GEMM (bf16 A, fp32 out), 64x128 tile, 2 blocks/CU ----------------
__global__ __launch_bounds__(256, 3) void gemm_out(
    const unsigned short* __restrict__ Abf, const unsigned short* __restrict__ W,
    const float* __restrict__ bias, float* __restrict__ outf) {
  const int id0 = blockIdx.x;
  const int l = (id0 & 7) * 64 + (id0 >> 3);   // bijective: 512 = 8*64
  const int m0 = (l >> 2) * 64, n0 = (l & 3) * 128;
  const int tid = threadIdx.x;
  const int wid = tid >> 6, lane = tid & 63;
  const int lr = lane & 15, lg = lane >> 4;
  const int wr = wid >> 1, wc = wid & 1;

  __shared__ __align__(16) unsigned short As[64 * 64];
  __shared__ __align__(16) unsigned short Bs[128 * 64];

  auto stage = [&](int k0) {
#pragma unroll
    for (int i = 0; i < 2; ++i) {
      const int ch = i * 256 + tid;
      const int r = ch >> 3, s = ch & 7;
      gload_lds16(Abf + (size_t)(m0 + r) * F_ + k0 + ((s ^ (r & 7)) * 8),
                  &As[(i * 256 + wid * 64) * 8]);
    }
#pragma unroll
    for (int i = 0; i < 4; ++i) {
      const int ch = i * 256 + tid;
      const int r = ch >> 3, s = ch & 7;
      gload_lds16(W + (size_t)(n0 + r) * F_ + k0 + ((s ^ (r & 7)) * 8),
                  &Bs[(i * 256 + wid * 64) * 8]);
    }
  };

  f32x4 acc[2][4] = {};
  for (int k0 = 0; k0 < F_; k0 += 64) {
    stage(k0);
    __syncthreads();
#pragma unroll
    for (int kk = 0; kk < 2; ++kk) {
      bf16x8 af[2], bf[4];
      const int slotA = (kk * 4 + lg) ^ (lr & 7);
#pragma unroll
      for (int m = 0; m < 2; ++m)
        af[m] = *(const bf16x8*)&As[(wr * 32 + m * 16 + lr) * 64 + slotA * 8];
#pragma unroll
      for (int n = 0; n < 4; ++n)
        bf[n] = *(const bf16x8*)&Bs[(wc * 64 + n * 16 + lr) * 64 + slotA * 8];
#pragma unroll
      for (int m = 0; m < 2; ++m)
#pragma unroll
        for (int n = 0; n < 4; ++n)
          acc[m][n] = __builtin_amdgcn_mfma_f32_16x16x32_bf16(af[m], bf[n], acc[m][n], 0, 0, 0);
    }
    __syncthreads();
  }

#pragma unroll
  for (int n = 0; n < 4; ++n) {
    const int col = n0 + wc * 64 + n * 16 + lr;
    const float bvv = bias[col];
#pragma unroll
    for (int m = 0; m < 2; ++m) {
      const int rbase = m0 + wr * 32 + m * 16 + lg * 4;
#pragma unroll
      for (int j = 0; j < 4; ++j)
        outf[(size_t)(rbase + j) * F_ + col] = acc[m][n][j] + bvv;
    }
  }
}

// ---------------- flash attention: 8 waves x 32 q, 256-kv staging, ring-2 ----------------
// R13 structure (2 waves/SIMD — occupancy is the binding resource; R14's 1-wave/SIMD
// variant regressed 1.7x). KV staged 256 at a time into a 2-buffer ring (128 KB LDS);
// ONE vmcnt(0)+barrier per staged tile (half the barriers of 128-staging); stage(t+1)
// issued at tile top lands during two 128-half compute passes. Per-128 compute body is
// the verified R13 code. Fixed-shift softmax; ones-MFMA denominator.
__global__ __launch_bounds__(512, 1) void attn_kernel(
    const unsigned short* __restrict__ Qp,
    const unsigned short* __restrict__ Kp,
    const unsigned short* __restrict__ Vt,
    const int* __restrict__ nbuf,
    unsigned short* __restrict__ X) {
  const int tid = threadIdx.x, wid = tid >> 6, lane = tid & 63;
  const int la = lane & 31, hi = lane >> 5;
  const int id = blockIdx.x;                  // 0..255, XCD-aware bijective swizzle
  const int swz = (id & 7) * 32 + (id >> 3);
  const int bh = swz >> 3, qb = swz & 7;
  const int b = bh >> 3, h = bh & 7;
  const int qrow = qb * 256 + wid * 32 + la;
  const int nb = nbuf[b];
  const int nt = (nb + 255) >> 8;             // staged 256-tiles

  __shared__ __align__(16) unsigned short Ks[2][2 * 128 * 64];  // two 128-halves, R13 layout
  __shared__ __align__(16) unsigned short Vs[2][2 * 64 * 128];

  bf16x8 qf[4];
#pragma unroll
  for (int kk = 0; kk < 4; ++kk)
    qf[kk] = *(const bf16x8*)(Qp + (size_t)(b * T_ + qrow) * F_ + h * DK_ + kk * 16 + hi * 8);

  union { unsigned short u[8]; bf16x8 v; } ones;
#pragma unroll
  for (int j = 0; j < 8; ++j) ones.u[j] = 0x3F80;   // bf16 1.0

  f32x16 oacc[2] = {};
  f32x16 dacc = {};

  auto stage = [&](int buf, int kv0) {
#pragma unroll
    for (int i = 0; i < 4; ++i) {
      const int ch = i * 512 + tid;            // 0..2047
      const int r = ch >> 3, s = ch & 7;       // K: 256 rows x 8 slots
      gload_lds16(Kp + (size_t)(b * T_ + kv0 + r) * F_ + h * DK_ + ((s ^ (r & 7)) * 8),
                  &Ks[buf][(i * 512 + wid * 64) * 8]);
      const int vh = ch >> 10, d = (ch >> 4) & 63, s2 = ch & 15;  // V: 2 halves x 64 rows x 16 slots
      gload_lds16(Vt + ((size_t)bh * DK_ + d) * T_ + kv0 + vh * 128 + ((s2 ^ (d & 15)) * 8),
                  &Vs[buf][(i * 512 + wid * 64) * 8]);
    }
  };

  if (nt > 0) {
    stage(0, 0);                                // 8 loads/thread
    int cur = 0;
    for (int t = 0; t < nt; ++t) {
      asm volatile("s_waitcnt vmcnt(0)" ::: "memory");   // stage(t) landed (issued a full tile ago)
      __builtin_amdgcn_s_barrier();
      __builtin_amdgcn_sched_barrier(0);
      if (t + 1 < nt) stage(cur ^ 1, (t + 1) * 256);     // lands during this tile's compute

#pragma unroll
      for (int half = 0; half < 2; ++half) {
        const int kv0 = t * 256 + half * 128;
        const unsigned short* pK = &Ks[cur][half * 8192];
        const unsigned short* pV = &Vs[cur][half * 8192];

        // S^T = K · Q^T, 4 blocks of 32 kv each
        f32x16 sb[4];
        __builtin_amdgcn_s_setprio(1);
#pragma unroll
        for (int n = 0; n < 4; ++n) {
          bf16x8 kf[4];
#pragma unroll
          for (int kk = 0; kk < 4; ++kk)
            kf[kk] = *(const bf16x8*)&pK[(n * 32 + la) * 64 + ((((kk << 1) | hi) ^ (la & 7)) * 8)];
          f32x16 s = {};
#pragma unroll
          for (int kk = 0; kk < 4; ++kk)
            s = __builtin_amdgcn_mfma_f32_32x32x16_bf16(kf[kk], qf[kk], s, 0, 0, 0);
          sb[n] = s;
        }
        __builtin_amdgcn_s_setprio(0);

        // P = exp2(S), tail-masked to 0 via index compare (compacted kv valid iff kv < nb)
        if (kv0 + 128 > nb) {
          const int kvb = kv0 + 4 * hi;
#pragma unroll
          for (int n = 0; n < 4; ++n)
#pragma unroll
            for (int r = 0; r < 16; ++r) {
              const int kv = kvb + n * 32 + (r & 3) + 8 * (r >> 2);
              if (kv >= nb) sb[n][r] = -__builtin_inff();
            }
        }
#pragma unroll
        for (int n = 0; n < 4; ++n)
#pragma unroll
          for (int r = 0; r < 16; ++r)
            sb[n][r] = __builtin_amdgcn_exp2f(sb[n][r]);

        // pack P pairs to bf16 words; exchange halves via permlane32_swap
        unsigned lowr[4][2][2], uppr[4][2][2];
#pragma unroll
        for (int n = 0; n < 4; ++n)
#pragma unroll
          for (int gg = 0; gg < 2; ++gg)
#pragma unroll
            for (int hh = 0; hh < 2; ++hh) {
              unsigned xE = cvtpk(sb[n][4 * (2 * gg) + 2 * hh], sb[n][4 * (2 * gg) + 2 * hh + 1]);
              unsigned xO = cvtpk(sb[n][4 * (2 * gg + 1) + 2 * hh], sb[n][4 * (2 * gg + 1) + 2 * hh + 1]);
              asm("v_permlane32_swap_b32 %0, %1" : "+v"(xE), "+v"(xO));
              lowr[n][gg][hh] = xE;
              uppr[n][gg][hh] = xO;
            }

        // O^T += V^T · P^T; denominator via ones-row MFMA
#pragma unroll
        for (int kt = 0; kt < 8; ++kt) {
          const int n = kt >> 1, gg = kt & 1;
          union { unsigned w[4]; bf16x8 v; } pf;
          pf.w[0] = lowr[n][gg][0]; pf.w[1] = lowr[n][gg][1];
          pf.w[2] = uppr[n][gg][0]; pf.w[3] = uppr[n][gg][1];
          __builtin_amdgcn_s_setprio(1);
          dacc = __builtin_amdgcn_mfma_f32_32x32x16_bf16(ones.v, pf.v, dacc, 0, 0, 0);
#pragma unroll
          for (int m = 0; m < 2; ++m) {
            const int d = m * 32 + la;
            bf16x8 vfr = *(const bf16x8*)&pV[d * 128 + ((((kt << 1) | hi) ^ (d & 15)) * 8)];
            oacc[m] = __builtin_amdgcn_mfma_f32_32x32x16_bf16(vfr, pf.v, oacc[m], 0, 0, 0);
          }
          __builtin_amdgcn_s_setprio(0);
        }
      }

      cur ^= 1;
    }
  }

  const float inv = 1.0f / fmaxf(dacc[0], 1e-37f);
#pragma unroll
  for (int m = 0; m < 2; ++m)
#pragma unroll
    for (int g = 0; g < 4; ++g) {
      union { unsigned short u[4]; s16x4 v; } ov;
#pragma unroll
      for (int j = 0; j < 4; ++j) ov.u[j] = f2bf(oacc[m][4 * g + j] * inv);
      *(s16x4*)(X + (size_t)(b * T_ + qrow) * F_ + h * DK_ + m * 32 + 8 * g + 4 * hi) = ov.v;
    }
}

// ---------------- launcher ----------------
extern "C" void kernel_launch(void* const* d_in, const int* in_sizes, int n_in,
                              void* d_out, int out_size, void* d_ws, size_t ws_size,
                              hipStream_t stream) {
  const float* q  = (const float*)d_in[0];
  const float* k  = (const float*)d_in[1];
  const float* v  = (const float*)d_in[2];
  const int* mask = (const int*)d_in[3];
  const float* Wq = (const float*)d_in[4];
  const float* bq = (const float*)d_in[5];
  const float* Wk = (const float*)d_in[6];
  const float* bk = (const float*)d_in[7];
  const float* Wv = (const float*)d_in[8];
  const float* bv = (const float*)d_in[9];
  const float* Wo = (const float*)d_in[10];
  const float* bo = (const float*)d_in[11];
  float* out = (float*)d_out;

  unsigned short* ws = (unsigned short*)d_ws;
  unsigned short* wts   = ws;                               // 4*F*F = 1,048,576 us
  unsigned short* projq = wts + (size_t)4 * F_ * F_;        // BT*F (Q)
  unsigned short* kc    = projq + (size_t)BT_ * F_;         // BT*F (compacted K)
  unsigned short* vt    = kc + (size_t)BT_ * F_;            // BT*F (compacted V^T per head)
  unsigned short* xbuf  = vt + (size_t)BT_ * F_;            // BT*F (attn output)
  int* invidx  = (int*)(xbuf + (size_t)BT_ * F_);           // B*T int
  int* nbuf    = invidx + BT_;                              // B int

  const float kQScale = 0.18033688011112042f;  // (1/sqrt(64)) * log2(e)

  convert_scan<<<dim3(128, 5, 1), 256, 0, stream>>>(
      Wq, Wk, Wv, Wo, mask, wts, invidx, nbuf);
  gemm_qkv<<<dim3(768, 1, 1), 256, 0, stream>>>(
      q, k, v, wts, bq, bk, bv, invidx, nbuf, projq, kc, vt, kQScale);
  attn_kernel<<<dim3(256, 1, 1), 512, 0, stream>>>(
      projq, kc, vt, nbuf, xbuf);
  gemm_out<<<dim3(512, 1, 1), 256, 0, stream>>>(
      xbuf, wts + (size_t)3 * F_ * F_, bo, out);
}

// Round 17
// 68.575 us; speedup vs baseline: 1.1701x; 1.0507x over previous
//
#include <hip/hip_runtime.h>
#include <hip/hip_bf16.h>
#include <stdint.h>

#define B_ 4
#define T_ 2048
#define F_ 512
#define H_ 8
#define DK_ 64
#define BT_ (B_*T_)   // 8192

typedef short bf16x8 __attribute__((ext_vector_type(8)));
typedef short s16x4 __attribute__((ext_vector_type(4)));
typedef float f32x4 __attribute__((ext_vector_type(4)));
typedef float f32x16 __attribute__((ext_vector_type(16)));

__device__ __forceinline__ unsigned short f2bf(float f) {
  union { float f; unsigned u; } v; v.f = f;
  return (unsigned short)((v.u + 0x7fffu + ((v.u >> 16) & 1u)) >> 16);
}

__device__ __forceinline__ unsigned cvtpk(float lo, float hi) {
  unsigned w;
  asm("v_cvt_pk_bf16_f32 %0, %1, %2" : "=v"(w) : "v"(lo), "v"(hi));
  return w;
}

__device__ __forceinline__ void gload_lds16(const void* g, void* l) {
  __builtin_amdgcn_global_load_lds((const __attribute__((address_space(1))) void*)g,
                                   (__attribute__((address_space(3))) void*)l, 16, 0, 0);
}

// ---------------- fused: weight fp32->bf16 conversion + mask scan ----------------
__global__ void convert_scan(const float* __restrict__ wq, const float* __restrict__ wk,
                             const float* __restrict__ wv, const float* __restrict__ wo,
                             const int* __restrict__ mask,
                             unsigned short* __restrict__ dst, int* __restrict__ invidx,
                             int* __restrict__ nbuf) {
  const int seg = blockIdx.y;
  const int tid = threadIdx.x;
  if (seg == 4) {
    if (blockIdx.x >= 4) return;
    const int b = blockIdx.x;
    __shared__ int cnt[256];
    const int base = b * T_ + tid * 8;
    int4 a = *(const int4*)(mask + base);
    int4 d = *(const int4*)(mask + base + 4);
    int m[8] = {a.x, a.y, a.z, a.w, d.x, d.y, d.z, d.w};
    int c = 0;
#pragma unroll
    for (int i = 0; i < 8; ++i) c += (m[i] != 0);
    cnt[tid] = c;
    __syncthreads();
    for (int off = 1; off < 256; off <<= 1) {
      int v = (tid >= off) ? cnt[tid - off] : 0;
      __syncthreads();
      cnt[tid] += v;
      __syncthreads();
    }
    int excl = cnt[tid] - c;
#pragma unroll
    for (int i = 0; i < 8; ++i)
      if (m[i]) { invidx[b * T_ + excl] = tid * 8 + i; ++excl; }
    if (tid == 255) nbuf[b] = cnt[255];
    return;
  }
  const float* src = seg == 0 ? wq : (seg == 1 ? wk : (seg == 2 ? wv : wo));
  unsigned short* out = dst + (size_t)seg * F_ * F_;
  const int idx = (blockIdx.x * 256 + tid) * 8;
  float4 a = *(const float4*)(src + idx);
  float4 b = *(const float4*)(src + idx + 4);
  union { unsigned w[4]; bf16x8 v; } t;
  t.w[0] = cvtpk(a.x, a.y); t.w[1] = cvtpk(a.z, a.w);
  t.w[2] = cvtpk(b.x, b.y); t.w[3] = cvtpk(b.z, b.w);
  *(bf16x8*)(out + idx) = t.v;
}

// ---------------- fused QKV projection GEMM ----------------
// XCD-locality swizzle: the 4 n-blocks of each m-group land on ONE XCD, co-resident
// (3 blocks/CU), so the A-panel re-reads hit that XCD's L2.
// p=0: Q rows (pre-scaled); p=1: K mask-gathered -> compacted kc (row-major);
// p=2: V mask-gathered -> Vt [BH][DK][Tc] written TRANSPOSED in the epilogue.
__global__ __launch_bounds__(256, 3) void gemm_qkv(
    const float* __restrict__ qin, const float* __restrict__ kin, const float* __restrict__ vin,
    const unsigned short* __restrict__ Wbase,
    const float* __restrict__ bq, const float* __restrict__ bk, const float* __restrict__ bv,
    const int* __restrict__ invidx, const int* __restrict__ nbuf,
    unsigned short* __restrict__ projq, unsigned short* __restrict__ kc,
    unsigned short* __restrict__ vt, float qscale) {
  const int id0 = blockIdx.x;
  const int id = (id0 & 7) * 96 + (id0 >> 3);   // bijective: 768 = 8*96
  const int p = id >> 8, l = id & 255;
  const int tid = threadIdx.x;
  const int wid = tid >> 6, lane = tid & 63;
  const int lr = lane & 15, lg = lane >> 4;
  const int wr = wid >> 1, wc = wid & 1;
  const int n0 = (l & 3) * 128;

  const float* Af;
  const float* bias;
  float sc = 1.0f;
  int obase, j0 = 0, b = 0, nb = T_;
  if (p == 0) {
    obase = (l >> 2) * 128;
    Af = qin; bias = bq; sc = qscale;
  } else {
    b = l >> 6;
    j0 = ((l >> 2) & 15) * 128;
    nb = nbuf[b];
    if (j0 >= ((nb + 63) & ~63)) return;   // tile entirely beyond compacted range
    obase = b * T_ + j0;
    Af = (p == 1) ? kin : vin;
    bias = (p == 1) ? bk : bv;
  }
  const unsigned short* W = Wbase + (size_t)p * F_ * F_;

  __shared__ __align__(16) unsigned short As[128 * 64];
  __shared__ __align__(16) unsigned short Bs[128 * 64];

  int srcrow[4];
#pragma unroll
  for (int i = 0; i < 4; ++i) {
    const int r = (i * 256 + tid) >> 3;
    if (p == 0) srcrow[i] = obase + r;
    else {
      int j = j0 + r;
      if (j >= nb) j = nb - 1;               // clamp: duplicate a real row (masked later)
      srcrow[i] = b * T_ + invidx[b * T_ + j];
    }
  }

  float4 aR[4][2];
  auto loadA = [&](int k0) {
#pragma unroll
    for (int i = 0; i < 4; ++i) {
      const int s = (i * 256 + tid) & 7;
      const float* sp = Af + (size_t)srcrow[i] * F_ + k0 + s * 8;
      aR[i][0] = *(const float4*)sp;
      aR[i][1] = *(const float4*)(sp + 4);
    }
  };
  auto writeA = [&]() {
#pragma unroll
    for (int i = 0; i < 4; ++i) {
      const int ch = i * 256 + tid;
      const int r = ch >> 3, s = ch & 7;
      union { unsigned w[4]; bf16x8 v; } t;
      t.w[0] = cvtpk(aR[i][0].x, aR[i][0].y); t.w[1] = cvtpk(aR[i][0].z, aR[i][0].w);
      t.w[2] = cvtpk(aR[i][1].x, aR[i][1].y); t.w[3] = cvtpk(aR[i][1].z, aR[i][1].w);
      *(bf16x8*)&As[r * 64 + ((s ^ (r & 7)) * 8)] = t.v;
    }
  };
  auto stageB = [&](int k0) {
#pragma unroll
    for (int i = 0; i < 4; ++i) {
      const int ch = i * 256 + tid;
      const int r = ch >> 3, s = ch & 7;
      gload_lds16(W + (size_t)(n0 + r) * F_ + k0 + ((s ^ (r & 7)) * 8),
                  &Bs[(i * 256 + wid * 64) * 8]);
    }
  };

  f32x4 acc[4][4] = {};
  loadA(0);
  for (int k0 = 0; k0 < F_; k0 += 64) {
    stageB(k0);
    writeA();
    if (k0 + 64 < F_) loadA(k0 + 64);   // issue next A-loads BEFORE the barrier drain
    __syncthreads();

#pragma unroll
    for (int kk = 0; kk < 2; ++kk) {
      bf16x8 af[4], bf[4];
      const int slotA = (kk * 4 + lg) ^ (lr & 7);
#pragma unroll
      for (int m = 0; m < 4; ++m)
        af[m] = *(const bf16x8*)&As[(wr * 64 + m * 16 + lr) * 64 + slotA * 8];
#pragma unroll
      for (int n = 0; n < 4; ++n)
        bf[n] = *(const bf16x8*)&Bs[(wc * 64 + n * 16 + lr) * 64 + slotA * 8];
#pragma unroll
      for (int m = 0; m < 4; ++m)
#pragma unroll
        for (int n = 0; n < 4; ++n)
          acc[m][n] = __builtin_amdgcn_mfma_f32_16x16x32_bf16(af[m], bf[n], acc[m][n], 0, 0, 0);
    }
    __syncthreads();
  }

  if (p == 2) {
    // transposed write: Vt[((b*8 + h)*64 + d)*T + kv],  h = col>>6, d = col&63
#pragma unroll
    for (int n = 0; n < 4; ++n) {
      const int col = n0 + wc * 64 + n * 16 + lr;
      const float bvv = bias[col];
      unsigned short* vrow = vt + ((size_t)(b * 8 + (col >> 6)) * 64 + (col & 63)) * T_;
#pragma unroll
      for (int m = 0; m < 4; ++m) {
        const int kv = j0 + wr * 64 + m * 16 + lg * 4;
        union { unsigned short u[4]; s16x4 v; } ov;
#pragma unroll
        for (int j = 0; j < 4; ++j) ov.u[j] = f2bf(acc[m][n][j] + bvv);
        *(s16x4*)(vrow + kv) = ov.v;
      }
    }
  } else {
    unsigned short* outp = (p == 0) ? projq : kc;
#pragma unroll
    for (int n = 0; n < 4; ++n) {
      const int col = n0 + wc * 64 + n * 16 + lr;
      const float bvv = bias[col];
#pragma unroll
      for (int m = 0; m < 4; ++m) {
        const int rbase = obase + wr * 64 + m * 16 + lg * 4;
#pragma unroll
        for (int j = 0; j < 4; ++j)
          outp[(size_t)(rbase + j) * F_ + col] = f2bf((acc[m][n][j] + bvv) * sc);
      }
    }
  }
}

// ---------------- output projection GEMM (bf16 A, fp32 out), 64x128 tile, 2 blocks/CU ----------------
__global__ __launch_bounds__(256, 3) void gemm_out(
    const unsigned short* __restrict__ Abf, const unsigned short* __restrict__ W,
    const float* __restrict__ bias, float* __restrict__ outf) {
  const int id0 = blockIdx.x;
  const int l = (id0 & 7) * 64 + (id0 >> 3);   // bijective: 512 = 8*64
  const int m0 = (l >> 2) * 64, n0 = (l & 3) * 128;
  const int tid = threadIdx.x;
  const int wid = tid >> 6, lane = tid & 63;
  const int lr = lane & 15, lg = lane >> 4;
  const int wr = wid >> 1, wc = wid & 1;

  __shared__ __align__(16) unsigned short As[64 * 64];
  __shared__ __align__(16) unsigned short Bs[128 * 64];

  auto stage = [&](int k0) {
#pragma unroll
    for (int i = 0; i < 2; ++i) {
      const int ch = i * 256 + tid;
      const int r = ch >> 3, s = ch & 7;
      gload_lds16(Abf + (size_t)(m0 + r) * F_ + k0 + ((s ^ (r & 7)) * 8),
                  &As[(i * 256 + wid * 64) * 8]);
    }
#pragma unroll
    for (int i = 0; i < 4; ++i) {
      const int ch = i * 256 + tid;
      const int r = ch >> 3, s = ch & 7;
      gload_lds16(W + (size_t)(n0 + r) * F_ + k0 + ((s ^ (r & 7)) * 8),
                  &Bs[(i * 256 + wid * 64) * 8]);
    }
  };

  f32x4 acc[2][4] = {};
  for (int k0 = 0; k0 < F_; k0 += 64) {
    stage(k0);
    __syncthreads();
#pragma unroll
    for (int kk = 0; kk < 2; ++kk) {
      bf16x8 af[2], bf[4];
      const int slotA = (kk * 4 + lg) ^ (lr & 7);
#pragma unroll
      for (int m = 0; m < 2; ++m)
        af[m] = *(const bf16x8*)&As[(wr * 32 + m * 16 + lr) * 64 + slotA * 8];
#pragma unroll
      for (int n = 0; n < 4; ++n)
        bf[n] = *(const bf16x8*)&Bs[(wc * 64 + n * 16 + lr) * 64 + slotA * 8];
#pragma unroll
      for (int m = 0; m < 2; ++m)
#pragma unroll
        for (int n = 0; n < 4; ++n)
          acc[m][n] = __builtin_amdgcn_mfma_f32_16x16x32_bf16(af[m], bf[n], acc[m][n], 0, 0, 0);
    }
    __syncthreads();
  }

#pragma unroll
  for (int n = 0; n < 4; ++n) {
    const int col = n0 + wc * 64 + n * 16 + lr;
    const float bvv = bias[col];
#pragma unroll
    for (int m = 0; m < 2; ++m) {
      const int rbase = m0 + wr * 32 + m * 16 + lg * 4;
#pragma unroll
      for (int j = 0; j < 4; ++j)
        outf[(size_t)(rbase + j) * F_ + col] = acc[m][n][j] + bvv;
    }
  }
}

// ---------------- flash attention: 8 waves, 3-deep pipeline, counted vmcnt (R13) ----------------
// 512 threads = 8 waves x 32 q-rows = 256 q/block; grid 256 = 1 block/CU (2 waves/SIMD).
// KV tile 128, THREE LDS buffers (96 KB): per tile wait vmcnt(4) (own stage landed,
// next stage's 4 loads stay in flight across the raw s_barrier) — never vmcnt(0) mid-loop.
// FIXED-SHIFT softmax; denominator via ones-row MFMA. [R14 1-wave/SIMD and R15 256-stage
// ring-2 variants both measured SLOWER — occupancy and counted-vmcnt depth are binding.]
__global__ __launch_bounds__(512, 1) void attn_kernel(
    const unsigned short* __restrict__ Qp,
    const unsigned short* __restrict__ Kp,
    const unsigned short* __restrict__ Vt,
    const int* __restrict__ nbuf,
    unsigned short* __restrict__ X) {
  const int tid = threadIdx.x, wid = tid >> 6, lane = tid & 63;
  const int la = lane & 31, hi = lane >> 5;
  const int id = blockIdx.x;                  // 0..255, XCD-aware bijective swizzle
  const int swz = (id & 7) * 32 + (id >> 3);
  const int bh = swz >> 3, qb = swz & 7;
  const int b = bh >> 3, h = bh & 7;
  const int qrow = qb * 256 + wid * 32 + la;
  const int nb = nbuf[b];
  const int nt = (nb + 127) >> 7;             // compacted 128-tile count

  __shared__ __align__(16) unsigned short Ks[3][128 * 64];  // [kv][dk], 8-slot XOR swizzle
  __shared__ __align__(16) unsigned short Vs[3][64 * 128];  // [d][kv], 16-slot XOR swizzle

  bf16x8 qf[4];
#pragma unroll
  for (int kk = 0; kk < 4; ++kk)
    qf[kk] = *(const bf16x8*)(Qp + (size_t)(b * T_ + qrow) * F_ + h * DK_ + kk * 16 + hi * 8);

  union { unsigned short u[8]; bf16x8 v; } ones;
#pragma unroll
  for (int j = 0; j < 8; ++j) ones.u[j] = 0x3F80;   // bf16 1.0

  f32x16 oacc[2] = {};
  f32x16 dacc = {};

  auto stage = [&](int buf, int kv0) {
#pragma unroll
    for (int i = 0; i < 2; ++i) {
      const int ch = i * 512 + tid;            // K: 1024 chunks of 16B over 512 threads
      const int r = ch >> 3, s = ch & 7;
      gload_lds16(Kp + (size_t)(b * T_ + kv0 + r) * F_ + h * DK_ + ((s ^ (r & 7)) * 8),
                  &Ks[buf][(i * 512 + wid * 64) * 8]);
      const int d = ch >> 4, s2 = ch & 15;     // V: 1024 chunks of 16B
      gload_lds16(Vt + ((size_t)bh * DK_ + d) * T_ + kv0 + ((s2 ^ (d & 15)) * 8),
                  &Vs[buf][(i * 512 + wid * 64) * 8]);
    }
  };

  if (nt > 0) {
    stage(0, 0);                                // 4 loads/thread
    if (nt > 1) stage(1, 128);                  // 4 more

    int cur = 0;
    for (int t = 0; t < nt; ++t) {
      // own stage(t) landed; stage(t+1)'s 4 loads may stay in flight (T4 counted vmcnt)
      if (t + 1 < nt) asm volatile("s_waitcnt vmcnt(4)" ::: "memory");
      else            asm volatile("s_waitcnt vmcnt(0)" ::: "memory");
      __builtin_amdgcn_s_barrier();
      __builtin_amdgcn_sched_barrier(0);
      if (t + 2 < nt) {
        int nxt = cur + 2; if (nxt >= 3) nxt -= 3;
        stage(nxt, (t + 2) * 128);              // overwrites buf last read at t-1 (pre-barrier)
      }
      const int kv0 = t * 128;

      // S^T = K · Q^T, 4 blocks of 32 kv each
      f32x16 sb[4];
      __builtin_amdgcn_s_setprio(1);
#pragma unroll
      for (int n = 0; n < 4; ++n) {
        bf16x8 kf[4];
#pragma unroll
        for (int kk = 0; kk < 4; ++kk)
          kf[kk] = *(const bf16x8*)&Ks[cur][(n * 32 + la) * 64 + ((((kk << 1) | hi) ^ (la & 7)) * 8)];
        f32x16 s = {};
#pragma unroll
        for (int kk = 0; kk < 4; ++kk)
          s = __builtin_amdgcn_mfma_f32_32x32x16_bf16(kf[kk], qf[kk], s, 0, 0, 0);
        sb[n] = s;
      }
      __builtin_amdgcn_s_setprio(0);

      // P = exp2(S), tail-masked to 0 via index compare (compacted kv valid iff kv < nb)
      if (kv0 + 128 > nb) {
        const int kvb = kv0 + 4 * hi;
#pragma unroll
        for (int n = 0; n < 4; ++n)
#pragma unroll
          for (int r = 0; r < 16; ++r) {
            const int kv = kvb + n * 32 + (r & 3) + 8 * (r >> 2);
            if (kv >= nb) sb[n][r] = -__builtin_inff();
          }
      }
#pragma unroll
      for (int n = 0; n < 4; ++n)
#pragma unroll
        for (int r = 0; r < 16; ++r)
          sb[n][r] = __builtin_amdgcn_exp2f(sb[n][r]);

      // pack P pairs to bf16 words; exchange halves via permlane32_swap
      unsigned lowr[4][2][2], uppr[4][2][2];
#pragma unroll
      for (int n = 0; n < 4; ++n)
#pragma unroll
        for (int gg = 0; gg < 2; ++gg)
#pragma unroll
          for (int hh = 0; hh < 2; ++hh) {
            unsigned xE = cvtpk(sb[n][4 * (2 * gg) + 2 * hh], sb[n][4 * (2 * gg) + 2 * hh + 1]);
            unsigned xO = cvtpk(sb[n][4 * (2 * gg + 1) + 2 * hh], sb[n][4 * (2 * gg + 1) + 2 * hh + 1]);
            asm("v_permlane32_swap_b32 %0, %1" : "+v"(xE), "+v"(xO));
            lowr[n][gg][hh] = xE;
            uppr[n][gg][hh] = xO;
          }

      // O^T += V^T · P^T; denominator via ones-row MFMA (all output rows = sum_k P[k][q])
#pragma unroll
      for (int kt = 0; kt < 8; ++kt) {
        const int n = kt >> 1, gg = kt & 1;
        union { unsigned w[4]; bf16x8 v; } pf;
        pf.w[0] = lowr[n][gg][0]; pf.w[1] = lowr[n][gg][1];
        pf.w[2] = uppr[n][gg][0]; pf.w[3] = uppr[n][gg][1];
        __builtin_amdgcn_s_setprio(1);
        dacc = __builtin_amdgcn_mfma_f32_32x32x16_bf16(ones.v, pf.v, dacc, 0, 0, 0);
#pragma unroll
        for (int m = 0; m < 2; ++m) {
          const int d = m * 32 + la;
          bf16x8 vfr = *(const bf16x8*)&Vs[cur][d * 128 + ((((kt << 1) | hi) ^ (d & 15)) * 8)];
          oacc[m] = __builtin_amdgcn_mfma_f32_32x32x16_bf16(vfr, pf.v, oacc[m], 0, 0, 0);
        }
        __builtin_amdgcn_s_setprio(0);
      }

      cur = (cur + 1 < 3) ? cur + 1 : 0;
    }
  }

  const float inv = 1.0f / fmaxf(dacc[0], 1e-37f);
#pragma unroll
  for (int m = 0; m < 2; ++m)
#pragma unroll
    for (int g = 0; g < 4; ++g) {
      union { unsigned short u[4]; s16x4 v; } ov;
#pragma unroll
      for (int j = 0; j < 4; ++j) ov.u[j] = f2bf(oacc[m][4 * g + j] * inv);
      *(s16x4*)(X + (size_t)(b * T_ + qrow) * F_ + h * DK_ + m * 32 + 8 * g + 4 * hi) = ov.v;
    }
}

// ---------------- launcher ----------------
extern "C" void kernel_launch(void* const* d_in, const int* in_sizes, int n_in,
                              void* d_out, int out_size, void* d_ws, size_t ws_size,
                              hipStream_t stream) {
  const float* q  = (const float*)d_in[0];
  const float* k  = (const float*)d_in[1];
  const float* v  = (const float*)d_in[2];
  const int* mask = (const int*)d_in[3];
  const float* Wq = (const float*)d_in[4];
  const float* bq = (const float*)d_in[5];
  const float* Wk = (const float*)d_in[6];
  const float* bk = (const float*)d_in[7];
  const float* Wv = (const float*)d_in[8];
  const float* bv = (const float*)d_in[9];
  const float* Wo = (const float*)d_in[10];
  const float* bo = (const float*)d_in[11];
  float* out = (float*)d_out;

  unsigned short* ws = (unsigned short*)d_ws;
  unsigned short* wts   = ws;                               // 4*F*F = 1,048,576 us
  unsigned short* projq = wts + (size_t)4 * F_ * F_;        // BT*F (Q)
  unsigned short* kc    = projq + (size_t)BT_ * F_;         // BT*F (compacted K)
  unsigned short* vt    = kc + (size_t)BT_ * F_;            // BT*F (compacted V^T per head)
  unsigned short* xbuf  = vt + (size_t)BT_ * F_;            // BT*F (attn output)
  int* invidx  = (int*)(xbuf + (size_t)BT_ * F_);           // B*T int
  int* nbuf    = invidx + BT_;                              // B int

  const float kQScale = 0.18033688011112042f;  // (1/sqrt(64)) * log2(e)

  convert_scan<<<dim3(128, 5, 1), 256, 0, stream>>>(
      Wq, Wk, Wv, Wo, mask, wts, invidx, nbuf);
  gemm_qkv<<<dim3(768, 1, 1), 256, 0, stream>>>(
      q, k, v, wts, bq, bk, bv, invidx, nbuf, projq, kc, vt, kQScale);
  attn_kernel<<<dim3(256, 1, 1), 512, 0, stream>>>(
      projq, kc, vt, nbuf, xbuf);
  gemm_out<<<dim3(512, 1, 1), 256, 0, stream>>>(
      xbuf, wts + (size_t)3 * F_ * F_, bo, out);
}